// Round 1
// baseline (499.794 us; speedup 1.0000x reference)
//
#include <hip/hip_runtime.h>
#include <math.h>

// Coverage attention. B=64, S=2048, H=512.
// e_t[b,s] = v_b + sum_h v_w[h] * tanh( (enc@Wh)[b,s,h] + D[b,h] + cov[b,s]*Wc[h] )
//   D[b,h] = (dec @ Ws)[b,h] + bs[h] + bh[h] + bc[h]
// out = [softmax(e_t) | coverage + softmax(e_t)]
//
// R4: occupancy-first restructure of the fused GEMM.
//  - 16 rows/wave (A frags = 64 VGPR, was 128) -> 4 waves/SIMD via
//    __launch_bounds__(512,4); 512-thr blocks, RPB=128, grid 1024.
//  - B (tiny, L2-hot) pre-laid by transpose_cast in EXACT per-phase LDS
//    fragment order; staged with global_load_lds dwordx4 (fire-and-forget
//    DMA, no staging VGPRs/VALU), double-buffered 2x32 KB, issued one
//    phase ahead, drained by the phase-end __syncthreads (vmcnt(0)).
//  - Frag reads are lane-permutations of contiguous 1 KB chunks ->
//    conflict-free ds_read_b128 with identity layout (no XOR needed).
//  - All accumulation orders identical to R3 -> bit-exact outputs.

#define B_ 64
#define S_ 2048
#define H_ 512
#define M_ (B_ * S_)

#define RPB 128   // rows per block (8 waves x 16)
#define BN 32     // n per phase
#define NPH 16    // phases = H_/BN
#define PHB 32768 // bytes per phase image (BN*H_*2)

typedef __attribute__((ext_vector_type(4))) float f32x4;
typedef __attribute__((ext_vector_type(8))) short s16x8;
typedef unsigned int u32;

__device__ __forceinline__ short f2bf(float f) {
    unsigned u = __float_as_uint(f);
    u += 0x7fffu + ((u >> 16) & 1u);  // RNE
    return (short)(u >> 16);
}

__device__ __forceinline__ s16x8 cvt8(float4 a, float4 b) {
    s16x8 r;
    r[0] = f2bf(a.x); r[1] = f2bf(a.y); r[2] = f2bf(a.z); r[3] = f2bf(a.w);
    r[4] = f2bf(b.x); r[5] = f2bf(b.y); r[6] = f2bf(b.z); r[7] = f2bf(b.w);
    return r;
}

__device__ __forceinline__ float fast_tanh(float x) {
    return 1.0f - 2.0f / (__expf(2.0f * x) + 1.0f);  // saturates correctly
}

// async global->LDS, 16B per lane. lds dest must be wave-uniform;
// HW writes at dest + lane*16. global src is per-lane.
__device__ __forceinline__ void dma16(const void* g, void* s) {
    __builtin_amdgcn_global_load_lds(
        (const __attribute__((address_space(1))) u32*)g,
        (__attribute__((address_space(3))) u32*)s, 16, 0, 0);
}

// Bimg: per-phase fragment-order image of bf16(Wh^T).
// short index = ph*16384 + kw*1024 + v*512 + ((q*16+ml))*8 + j
// holds bf16(Wh[k][n]) with n = ph*32 + v*16 + ml, k = kw*32 + q*8 + j.
__global__ __launch_bounds__(256) void transpose_cast(
    const float* __restrict__ Wh, short* __restrict__ Bimg) {
    __shared__ float tile[32][33];
    const int n0 = blockIdx.x * 32, k0 = blockIdx.y * 32;
    const int tx = threadIdx.x & 31, ty = threadIdx.x >> 5;  // 32 x 8
#pragma unroll
    for (int r = 0; r < 32; r += 8)
        tile[ty + r][tx] = Wh[(size_t)(k0 + ty + r) * H_ + n0 + tx];
    __syncthreads();
    const int kw = k0 >> 5;            // k0 is a multiple of 32
    const int q = tx >> 3, j = tx & 7; // k = k0 + tx = kw*32 + q*8 + j
#pragma unroll
    for (int r = 0; r < 32; r += 8) {
        const int n = n0 + ty + r;
        const int ph = n >> 5, v = (n >> 4) & 1, mln = n & 15;
        const size_t idx = (size_t)ph * 16384 + (size_t)kw * 1024 + v * 512
                         + (q * 16 + mln) * 8 + j;
        Bimg[idx] = f2bf(tile[tx][ty + r]);  // element (k=k0+tx, n)
    }
}

// D[b,h] = dec[b,:] . Ws[:,h] + bs[h] + bh[h] + bc[h]
// (identical per-element math order to R3; 2 h-slabs for 2x parallelism)
__global__ __launch_bounds__(256) void dec_kernel(
    const float* __restrict__ dh, const float* __restrict__ Ws,
    const float* __restrict__ bs, const float* __restrict__ bh,
    const float* __restrict__ bc, float* __restrict__ D) {
    const int b = blockIdx.x;
    const int h = blockIdx.y * 256 + threadIdx.x;
    __shared__ float sdh[H_];
    sdh[threadIdx.x] = dh[b * H_ + threadIdx.x];
    sdh[threadIdx.x + 256] = dh[b * H_ + threadIdx.x + 256];
    __syncthreads();
    float acc = bs[h] + bh[h] + bc[h];
#pragma unroll 8
    for (int k = 0; k < H_; ++k)
        acc = fmaf(sdh[k], Ws[k * H_ + h], acc);
    D[b * H_ + h] = acc;
}

__global__ __launch_bounds__(512, 4) void gemm_fused(
    const float* __restrict__ A,      // [M_, H_] fp32 encoder
    const short* __restrict__ Bimg,   // phase-frag image of bf16(Wh^T)
    const float* __restrict__ cover,  // [M_]
    const float* __restrict__ Wc,     // [H_]
    const float* __restrict__ vw,     // [H_]
    const float* __restrict__ D,      // [B_, H_]
    float* __restrict__ e_t) {        // [M_] final logits (minus v_b)
    __shared__ __align__(16) short Bs[2][BN * H_];  // 2 x 32768 B

    const int tid = threadIdx.x;
    const int w = tid >> 6;   // wave 0..7
    const int l = tid & 63;
    const int q = l >> 4;     // k-chunk (A/B) / row-quad (C)
    const int ml = l & 15;    // m (A) / n (B) within 16-tile

    const int row_blk = blockIdx.x * RPB;
    const int b = row_blk >> 11;      // /S_
    const int r0 = row_blk + w * 16;  // this wave's 16 rows

    // ---- prefetch phase 0 into buf 0 (4 x 1KB DMA per wave) ----
    {
        const char* g = (const char*)Bimg + (size_t)(w * 4) * 1024 + l * 16;
        char* s = (char*)&Bs[0][0] + (w * 4) * 1024;
#pragma unroll
        for (int c = 0; c < 4; ++c) dma16(g + c * 1024, s + c * 1024);
    }

    // ---- A fill: 16 rows, 16 k-windows, fp32->bf16 once ----
    s16x8 a[16];
    {
        const float* ap = A + (size_t)(r0 + ml) * H_ + q * 8;
#pragma unroll
        for (int kw = 0; kw < 16; ++kw) {
            float4 x = *(const float4*)(ap + kw * 32);
            float4 y = *(const float4*)(ap + kw * 32 + 4);
            a[kw] = cvt8(x, y);
        }
    }

    // coverage per C-row (C layout: col=ml, row=q*4+reg)
    float cv[4];
#pragma unroll
    for (int r = 0; r < 4; ++r) cv[r] = cover[r0 + q * 4 + r];

    float ecur[4] = {0.0f, 0.0f, 0.0f, 0.0f};

    __syncthreads();  // drains vmcnt(0): phase-0 stage complete

    for (int ph = 0; ph < NPH; ++ph) {
        const int cur = ph & 1;

        // stage next phase into the other buffer (fire-and-forget)
        if (ph + 1 < NPH) {
            const char* g = (const char*)Bimg + (size_t)(ph + 1) * PHB
                          + (size_t)(w * 4) * 1024 + l * 16;
            char* s = (char*)&Bs[cur ^ 1][0] + (w * 4) * 1024;
#pragma unroll
            for (int c = 0; c < 4; ++c) dma16(g + c * 1024, s + c * 1024);
        }

        // per-phase column params (L2-hot, hidden under MFMA loop)
        const int n0 = ph * BN + ml;
        const float wc0 = Wc[n0],          wc1 = Wc[n0 + 16];
        const float vv0 = vw[n0],          vv1 = vw[n0 + 16];
        const float dd0 = D[b * H_ + n0],  dd1 = D[b * H_ + n0 + 16];

        const short* bp = &Bs[cur][0];
        f32x4 acc0 = (f32x4)0.0f, acc1 = (f32x4)0.0f;
#pragma unroll
        for (int kw = 0; kw < 16; ++kw) {
            s16x8 b0 = *(const s16x8*)(bp + kw * 1024 + l * 8);
            s16x8 b1 = *(const s16x8*)(bp + kw * 1024 + 512 + l * 8);
            acc0 = __builtin_amdgcn_mfma_f32_16x16x32_bf16(a[kw], b0, acc0, 0, 0, 0);
            acc1 = __builtin_amdgcn_mfma_f32_16x16x32_bf16(a[kw], b1, acc1, 0, 0, 0);
        }

        // e partials: x = acc + cov*Wc + D; e += vw*tanh(x)
        // (same n-order as R3: v=0 then v=1, phases ascending)
#pragma unroll
        for (int r = 0; r < 4; ++r) {
            ecur[r] += vv0 * fast_tanh(acc0[r] + fmaf(cv[r], wc0, dd0));
            ecur[r] += vv1 * fast_tanh(acc1[r] + fmaf(cv[r], wc1, dd1));
        }

        __syncthreads();  // vmcnt(0)+lgkmcnt(0)+barrier: stage done, reads done
    }

    // final cross-lane (ml) reduction and store
    float p0 = ecur[0], p1 = ecur[1], p2 = ecur[2], p3 = ecur[3];
#pragma unroll
    for (int s = 1; s < 16; s <<= 1) {
        p0 += __shfl_xor(p0, s, 64);
        p1 += __shfl_xor(p1, s, 64);
        p2 += __shfl_xor(p2, s, 64);
        p3 += __shfl_xor(p3, s, 64);
    }
    if (ml == 0) {
        float4 st = {p0, p1, p2, p3};
        *(float4*)&e_t[r0 + q * 4] = st;
    }
}

__global__ __launch_bounds__(256) void softmax_kernel(
    const float* __restrict__ e_t, const float* __restrict__ cover,
    const float* __restrict__ vb, float* __restrict__ out) {
    const int b = blockIdx.x;
    const int tid = threadIdx.x;
    const float vbv = vb[0];

    float e[8];
    float mx = -1e30f;
#pragma unroll
    for (int r = 0; r < 8; ++r) {
        e[r] = e_t[b * S_ + r * 256 + tid] + vbv;
        mx = fmaxf(mx, e[r]);
    }
#pragma unroll
    for (int off = 32; off >= 1; off >>= 1) mx = fmaxf(mx, __shfl_xor(mx, off, 64));

    __shared__ float sm[4], ss[4], sbc[2];
    const int wid = tid >> 6, lane = tid & 63;
    if (lane == 0) sm[wid] = mx;
    __syncthreads();
    if (tid == 0) sbc[0] = fmaxf(fmaxf(sm[0], sm[1]), fmaxf(sm[2], sm[3]));
    __syncthreads();
    mx = sbc[0];

    float ex[8];
    float sum = 0.0f;
#pragma unroll
    for (int r = 0; r < 8; ++r) {
        ex[r] = __expf(e[r] - mx);
        sum += ex[r];
    }
#pragma unroll
    for (int off = 32; off >= 1; off >>= 1) sum += __shfl_xor(sum, off, 64);
    if (lane == 0) ss[wid] = sum;
    __syncthreads();
    if (tid == 0) sbc[1] = ss[0] + ss[1] + ss[2] + ss[3];
    __syncthreads();
    const float inv = 1.0f / sbc[1];

#pragma unroll
    for (int r = 0; r < 8; ++r) {
        const int s = r * 256 + tid;
        const float a = ex[r] * inv;
        out[b * S_ + s] = a;                           // a_t
        out[M_ + b * S_ + s] = cover[b * S_ + s] + a;  // sum_coverage
    }
}

extern "C" void kernel_launch(void* const* d_in, const int* in_sizes, int n_in,
                              void* d_out, int out_size, void* d_ws, size_t ws_size,
                              hipStream_t stream) {
    const float* enc = (const float*)d_in[0];
    const float* dh  = (const float*)d_in[1];
    const float* cov = (const float*)d_in[2];
    const float* Wh  = (const float*)d_in[3];
    const float* bh  = (const float*)d_in[4];
    const float* Ws  = (const float*)d_in[5];
    const float* bs  = (const float*)d_in[6];
    const float* Wc  = (const float*)d_in[7];
    const float* bc  = (const float*)d_in[8];
    const float* vw  = (const float*)d_in[9];
    const float* vb  = (const float*)d_in[10];
    float* out = (float*)d_out;

    float* e_t  = (float*)d_ws;              // M_ floats
    float* Dws  = e_t + M_;                  // B_*H_ floats
    short* Whbt = (short*)(Dws + B_ * H_);   // H_*H_ bf16 (phase-frag image)

    transpose_cast<<<dim3(H_ / 32, H_ / 32), 256, 0, stream>>>(Wh, Whbt);
    dec_kernel<<<dim3(B_, 2), 256, 0, stream>>>(dh, Ws, bs, bh, bc, Dws);
    gemm_fused<<<M_ / RPB, 512, 0, stream>>>(enc, Whbt, cov, Wc, vw, Dws, e_t);
    softmax_kernel<<<B_, 256, 0, stream>>>(e_t, cov, vb, out);
}